// Round 1
// baseline (2237.608 us; speedup 1.0000x reference)
//
#include <hip/hip_runtime.h>
#include <hip/hip_bf16.h>

// BitLinear: out[M,N] = (x[M,K] @ wq[N,K]^T) * scale
//   scale = max(mean|w|, 1e-5); wq = clip(round(w/scale), -1, 1)  (ternary)
// M = 4*2048 = 8192, K = 4096, N = 16384. fp32 in/out.

#define K_DIM 4096
#define N_DIM 16384
#define M_DIM 8192

static constexpr size_t W_ELEMS = (size_t)N_DIM * K_DIM;  // 67108864
static constexpr size_t X_ELEMS = (size_t)M_DIM * K_DIM;  // 33554432

typedef __attribute__((ext_vector_type(8))) short bf16x8;
typedef __attribute__((ext_vector_type(4))) float f32x4;

__device__ __forceinline__ float get_scale(const double* __restrict__ sumabs) {
  double mean = *sumabs * (1.0 / (double)W_ELEMS);
  double s = mean > 1e-5 ? mean : 1e-5;
  return (float)s;
}

// ---------------- pass 1: sum |w| (double accumulation) ----------------
__global__ void absum_kernel(const float* __restrict__ w, double* __restrict__ out) {
  __shared__ double sd[256];
  const float4* w4 = (const float4*)w;
  const size_t n4 = W_ELEMS / 4;
  const size_t stride = (size_t)gridDim.x * blockDim.x;
  double acc = 0.0;
  for (size_t i = (size_t)blockIdx.x * blockDim.x + threadIdx.x; i < n4; i += stride) {
    float4 v = w4[i];
    acc += ((double)fabsf(v.x) + (double)fabsf(v.y)) +
           ((double)fabsf(v.z) + (double)fabsf(v.w));
  }
  sd[threadIdx.x] = acc;
  __syncthreads();
  for (int s = 128; s > 0; s >>= 1) {
    if ((int)threadIdx.x < s) sd[threadIdx.x] += sd[threadIdx.x + s];
    __syncthreads();
  }
  if (threadIdx.x == 0) atomicAdd(out, sd[0]);
}

// ---------------- pass 2: x -> bf16 ----------------
__global__ void cvtx_kernel(const float* __restrict__ x, ushort* __restrict__ xb) {
  const size_t n4 = X_ELEMS / 4;
  const size_t stride = (size_t)gridDim.x * blockDim.x;
  for (size_t i = (size_t)blockIdx.x * blockDim.x + threadIdx.x; i < n4; i += stride) {
    float4 v = ((const float4*)x)[i];
    __hip_bfloat16 h0 = __float2bfloat16(v.x);
    __hip_bfloat16 h1 = __float2bfloat16(v.y);
    __hip_bfloat16 h2 = __float2bfloat16(v.z);
    __hip_bfloat16 h3 = __float2bfloat16(v.w);
    ushort4 o;
    o.x = *(ushort*)&h0; o.y = *(ushort*)&h1; o.z = *(ushort*)&h2; o.w = *(ushort*)&h3;
    ((ushort4*)xb)[i] = o;
  }
}

// ---------------- pass 3: w -> ternary bf16 ----------------
__device__ __forceinline__ ushort qbits(float w, float scale) {
  float q = rintf(w / scale);           // round-half-to-even, matches jnp.round
  q = fminf(1.0f, fmaxf(-1.0f, q));
  __hip_bfloat16 b = __float2bfloat16(q);  // exact for {-1,0,1}
  return *(ushort*)&b;
}

__global__ void quant_kernel(const float* __restrict__ w, const double* __restrict__ sumabs,
                             ushort* __restrict__ wq) {
  const float scale = get_scale(sumabs);
  const size_t n4 = W_ELEMS / 4;
  const size_t stride = (size_t)gridDim.x * blockDim.x;
  for (size_t i = (size_t)blockIdx.x * blockDim.x + threadIdx.x; i < n4; i += stride) {
    float4 v = ((const float4*)w)[i];
    ushort4 o;
    o.x = qbits(v.x, scale);
    o.y = qbits(v.y, scale);
    o.z = qbits(v.z, scale);
    o.w = qbits(v.w, scale);
    ((ushort4*)wq)[i] = o;
  }
}

// ---------------- pass 4: GEMM (bf16 MFMA), epilogue * scale ----------------
// 128x128 tile, BK=32, 4 waves (2x2), each wave 64x64 = 4x4 MFMA 16x16x32.
// Staging: global_load_lds width 16, linear LDS dest; XOR swizzle
// (q' = q ^ ((row>>1)&3)) applied to the GLOBAL source and to the ds_read
// address (same involution both sides).
__global__ __launch_bounds__(256, 2)
void gemm_kernel(const ushort* __restrict__ X, const ushort* __restrict__ W,
                 const double* __restrict__ sumabs, float* __restrict__ C) {
  __shared__ alignas(128) char lds[16384];  // As [0,8192), Bs [8192,16384)

  // XCD-bijective swizzle: gridDim.x = 8192 divisible by 8
  const int bid = blockIdx.x;
  const int cpx = gridDim.x >> 3;
  const int swz = (bid & 7) * cpx + (bid >> 3);
  const int bm = swz >> 7;   // 0..63   (M/128)
  const int bn = swz & 127;  // 0..127  (N/128)

  const int t = threadIdx.x;
  const int wave = t >> 6;
  const int lane = t & 63;

  // per-thread staging source addresses (pre-swizzled global source)
  const char* asrc[2];
  const char* bsrc[2];
#pragma unroll
  for (int c = 0; c < 2; ++c) {
    int s = c * 256 + t;          // 16B slot index 0..511
    int row = s >> 2;             // 0..127
    int q = (s & 3) ^ ((row >> 1) & 3);
    asrc[c] = (const char*)(X + ((size_t)(bm * 128 + row) * K_DIM + q * 8));
    bsrc[c] = (const char*)(W + ((size_t)(bn * 128 + row) * K_DIM + q * 8));
  }

  // fragment ds_read offsets (swizzled)
  int aoff[4], boff[4];
  {
    int q = lane >> 4;
#pragma unroll
    for (int i = 0; i < 4; ++i) {
      int ra = (wave >> 1) * 64 + i * 16 + (lane & 15);
      aoff[i] = ra * 64 + ((q ^ ((ra >> 1) & 3)) << 4);
      int rb = (wave & 1) * 64 + i * 16 + (lane & 15);
      boff[i] = 8192 + rb * 64 + ((q ^ ((rb >> 1) & 3)) << 4);
    }
  }

  f32x4 acc[4][4];
#pragma unroll
  for (int i = 0; i < 4; ++i)
#pragma unroll
    for (int j = 0; j < 4; ++j)
      acc[i][j] = (f32x4){0.f, 0.f, 0.f, 0.f};

  for (int k0 = 0; k0 < K_DIM; k0 += 32) {
#pragma unroll
    for (int c = 0; c < 2; ++c) {
      __builtin_amdgcn_global_load_lds(
          (const __attribute__((address_space(1))) void*)asrc[c],
          (__attribute__((address_space(3))) void*)(lds + c * 4096 + wave * 1024),
          16, 0, 0);
      __builtin_amdgcn_global_load_lds(
          (const __attribute__((address_space(1))) void*)bsrc[c],
          (__attribute__((address_space(3))) void*)(lds + 8192 + c * 4096 + wave * 1024),
          16, 0, 0);
      asrc[c] += 64;  // BK=32 bf16 = 64 bytes
      bsrc[c] += 64;
    }
    __syncthreads();  // compiler emits vmcnt(0) drain before s_barrier

    bf16x8 af[4], bfr[4];
#pragma unroll
    for (int i = 0; i < 4; ++i) {
      af[i]  = *(const bf16x8*)(lds + aoff[i]);
      bfr[i] = *(const bf16x8*)(lds + boff[i]);
    }
#pragma unroll
    for (int i = 0; i < 4; ++i)
#pragma unroll
      for (int j = 0; j < 4; ++j)
        acc[i][j] = __builtin_amdgcn_mfma_f32_16x16x32_bf16(af[i], bfr[j], acc[i][j], 0, 0, 0);
    __syncthreads();
  }

  const float scale = get_scale(sumabs);
  // C/D layout: col = lane&15, row = (lane>>4)*4 + reg
  const int crow0 = bm * 128 + (wave >> 1) * 64 + (lane >> 4) * 4;
  const int ccol0 = bn * 128 + (wave & 1) * 64 + (lane & 15);
#pragma unroll
  for (int i = 0; i < 4; ++i)
#pragma unroll
    for (int j = 0; j < 4; ++j)
#pragma unroll
      for (int r = 0; r < 4; ++r)
        C[(size_t)(crow0 + i * 16 + r) * N_DIM + (ccol0 + j * 16)] = acc[i][j][r] * scale;
}

// ---------------- launcher ----------------
extern "C" void kernel_launch(void* const* d_in, const int* in_sizes, int n_in,
                              void* d_out, int out_size, void* d_ws, size_t ws_size,
                              hipStream_t stream) {
  const float* x = (const float*)d_in[0];   // [4,2048,4096]
  const float* w = (const float*)d_in[1];   // [16384,4096]
  float* out = (float*)d_out;               // [4,2048,16384]

  double* sumabs = (double*)d_ws;
  ushort* xb = (ushort*)((char*)d_ws + 1024);                    // 64 MiB
  ushort* wq = (ushort*)((char*)d_ws + 1024 + X_ELEMS * 2);      // 128 MiB

  hipMemsetAsync(d_ws, 0, 8, stream);
  absum_kernel<<<2048, 256, 0, stream>>>(w, sumabs);
  cvtx_kernel<<<2048, 256, 0, stream>>>(x, xb);
  quant_kernel<<<2048, 256, 0, stream>>>(w, sumabs, wq);
  gemm_kernel<<<8192, 256, 0, stream>>>(xb, wq, sumabs, out);
}